// Round 1
// baseline (526.505 us; speedup 1.0000x reference)
//
#include <hip/hip_runtime.h>

// BoxCrop: crop -> aspect-preserving bilinear resize (long side = 336) ->
// square pad (fill 127). B=64, C=3, H=W=768, fp32.
//
// One thread per output spatial pixel (b, oy, ox); loops the 3 channels
// (they share src coords + bilinear weights). 336*336 = 112896 = 441*256,
// so grid (441, B) x block 256 has no tail.

#define OUTS 336
#define FILLV 127.0f
#define NCH 3
#define IMH 768
#define IMW 768

__global__ __launch_bounds__(256) void boxcrop_kernel(
    const float* __restrict__ images,
    const int*   __restrict__ boxes,
    float*       __restrict__ out)
{
    const int b = blockIdx.y;
    const int p = blockIdx.x * 256 + threadIdx.x;   // 0 .. 112895
    const int oy = p / OUTS;
    const int ox = p - oy * OUTS;

    // Box params are uniform per block (b = blockIdx.y) -> scalar loads.
    const int xb = boxes[4 * b + 0];
    const int yb = boxes[4 * b + 1];
    const int wb = boxes[4 * b + 2];
    const int hb = boxes[4 * b + 3];

    const float wf = (float)wb;
    const float hf = (float)hb;
    const float scale = 336.0f / fmaxf(wf, hf);
    // jnp.round = round-half-even = rintf (default rounding mode)
    const int new_w = (int)rintf(wf * scale);
    const int new_h = (int)rintf(hf * scale);
    const int pad_top  = (hb < wb)  ? ((OUTS - new_h) >> 1) : 0;
    const int pad_left = (hb >= wb) ? ((OUTS - new_w) >> 1) : 0;

    const int iy = oy - pad_top;
    const int ix = ox - pad_left;
    const bool valid = (iy >= 0) & (iy < new_h) & (ix >= 0) & (ix < new_w);

    float r0 = FILLV, r1 = FILLV, r2 = FILLV;

    if (valid) {
        // Exact fp32 op order of the reference:
        //   src = box0 + ((i + 0.5) * len) / new_len - 0.5
        const float src_y = ((float)yb + (((float)iy + 0.5f) * hf) / (float)new_h) - 0.5f;
        const float src_x = ((float)xb + (((float)ix + 0.5f) * wf) / (float)new_w) - 0.5f;
        const float y0f = floorf(src_y);
        const float x0f = floorf(src_x);
        const float wy = src_y - y0f;
        const float wx = src_x - x0f;
        const int yhi = yb + hb - 1;
        const int xhi = xb + wb - 1;
        const int y0 = min(max((int)y0f,     yb), yhi);
        const int y1 = min(max((int)y0f + 1, yb), yhi);
        const int x0 = min(max((int)x0f,     xb), xhi);
        const int x1 = min(max((int)x0f + 1, xb), xhi);

        const size_t img_base = (size_t)b * NCH * IMH * IMW;
        const size_t r0off = (size_t)y0 * IMW;
        const size_t r1off = (size_t)y1 * IMW;

        const float omwx = 1.0f - wx;
        const float omwy = 1.0f - wy;

        #pragma unroll
        for (int c = 0; c < NCH; ++c) {
            const float* img = images + img_base + (size_t)c * IMH * IMW;
            const float v00 = img[r0off + x0];
            const float v01 = img[r0off + x1];
            const float v10 = img[r1off + x0];
            const float v11 = img[r1off + x1];
            const float top = v00 * omwx + v01 * wx;
            const float bot = v10 * omwx + v11 * wx;
            const float val = top * omwy + bot * wy;
            if (c == 0) r0 = val;
            else if (c == 1) r1 = val;
            else r2 = val;
        }
    }

    float* ob = out + ((size_t)b * NCH) * (OUTS * OUTS) + p;
    ob[0]                 = r0;
    ob[OUTS * OUTS]       = r1;
    ob[2 * OUTS * OUTS]   = r2;
}

extern "C" void kernel_launch(void* const* d_in, const int* in_sizes, int n_in,
                              void* d_out, int out_size, void* d_ws, size_t ws_size,
                              hipStream_t stream) {
    const float* images = (const float*)d_in[0];
    const int*   boxes  = (const int*)d_in[1];
    float*       out    = (float*)d_out;

    const int B = in_sizes[1] / 4;   // boxes is [B,4] int32
    dim3 grid((OUTS * OUTS) / 256, B, 1);   // 441 x B
    dim3 block(256, 1, 1);
    boxcrop_kernel<<<grid, block, 0, stream>>>(images, boxes, out);
}